// Round 6
// baseline (116.986 us; speedup 1.0000x reference)
//
#include <hip/hip_runtime.h>
#include <hip/hip_bf16.h>

#define C_ 8
#define B_ 32
#define G_ 2048
#define S_ 32
#define L_ 3
#define GB_ (G_ * B_)                 // 65536 items per clause

// ws float offsets
#define OFF_BUF0 0                     // [C][G][B] unnormalized R (gather source)
#define OFF_BUF1 524288                // [C][G][B] clause lse r
#define OFF_MAX  1048576               // cmax slots: (t*8+c)*16 -> 512 floats
#define OFF_GMAX (OFF_MAX + 512)       // gmax slots: t*16 -> 64 floats
#define OFF_XT   (OFF_MAX + 640)       // xT [G][B]
#define ZERO_FLOATS 576

#define IDXPAD 104                     // sIdx row stride (ints): 416B -> groups on disjoint banks

__device__ __forceinline__ void atomicMaxPos(float* a, float v) {
    // all values >= 0, so uint compare == float compare
    atomicMax((unsigned*)a, __float_as_uint(v));
}

// ---- build xT[g][b] = x[b][g]; zero the max slots ----
__global__ __launch_bounds__(1024) void k_init(const float* __restrict__ x,
                                               float* __restrict__ xT,
                                               float* __restrict__ maxs) {
    __shared__ float sT[32 * 33];
    const int tid = threadIdx.x, bid = blockIdx.x;    // 64 blocks x 1024
    const int g0 = bid * 32;
    sT[(tid & 31) * 33 + (tid >> 5)] = x[(tid >> 5) * G_ + g0 + (tid & 31)];
    __syncthreads();
    xT[(g0 + (tid >> 5)) * B_ + (tid & 31)] = sT[(tid >> 5) * 33 + (tid & 31)];
    if (bid == 0 && tid < ZERO_FLOATS) maxs[tid] = 0.0f;
}

// ---- clause: r = softor_S(prod_L R[c, I, b]), float2 per thread ----
// block = 256 threads = 16 rows x 16 b-halves; each thread -> 2 items.
__global__ __launch_bounds__(256, 4) void k_clause(const float* __restrict__ Rbase,
                                                   int cstride,                 // 0 at t=0
                                                   const int* __restrict__ I,
                                                   float* __restrict__ r_out,   // buf1
                                                   const float* __restrict__ gmax_prev,
                                                   float* __restrict__ cmax_step) {
    __shared__ int sIdx[16 * IDXPAD];   // 6.5 KB
    __shared__ float sRed[4];

    const int tid = threadIdx.x;
    const int bid = blockIdx.x;         // 1024 blocks, 16 rows each
    const int c = bid >> 7;             // 128 blocks per clause
    const int r0 = bid * 16;

    {   // stage 16x96 indices into padded rows
        const int* Ib = I + r0 * 96;
#pragma unroll
        for (int k = 0; k < 6; ++k) {
            const int j = tid + 256 * k;            // 0..1535
            const int row = j / 96, w = j - row * 96;
            sIdx[row * IDXPAD + w] = Ib[j];
        }
    }
    __syncthreads();

    const float gm = gmax_prev ? gmax_prev[0] : 0.0f;
    const float sc = (gm > 1.0f) ? (1.0f / gm) : 1.0f;
    const float sc3 = sc * sc * sc;

    const int bh = tid & 15;            // b-pair: covers b = 2bh, 2bh+1
    const int rowloc = tid >> 4;        // 0..15
    const float2* Rb2 = (const float2*)(Rbase + c * cstride) + bh;
    const int4* p = (const int4*)(sIdx + rowloc * IDXPAD);

    float2 mx = make_float2(-1e30f, -1e30f);
    float2 sum = make_float2(0.0f, 0.0f);
#pragma unroll
    for (int ch = 0; ch < 8; ++ch) {    // 4 substitutions per chunk, 12 float2 loads
        const int4 qa = p[ch * 3 + 0], qb = p[ch * 3 + 1], qc = p[ch * 3 + 2];
        const float2 v0 = Rb2[qa.x << 4], v1 = Rb2[qa.y << 4], v2 = Rb2[qa.z << 4];
        const float2 v3 = Rb2[qa.w << 4], v4 = Rb2[qb.x << 4], v5 = Rb2[qb.y << 4];
        const float2 v6 = Rb2[qb.z << 4], v7 = Rb2[qb.w << 4], v8 = Rb2[qc.x << 4];
        const float2 v9 = Rb2[qc.y << 4], va = Rb2[qc.z << 4], vb = Rb2[qc.w << 4];
        float2 b0, b1, b2, b3;
        b0.x = v0.x * v1.x * v2.x * sc3;  b0.y = v0.y * v1.y * v2.y * sc3;
        b1.x = v3.x * v4.x * v5.x * sc3;  b1.y = v3.y * v4.y * v5.y * sc3;
        b2.x = v6.x * v7.x * v8.x * sc3;  b2.y = v6.y * v7.y * v8.y * sc3;
        b3.x = v9.x * va.x * vb.x * sc3;  b3.y = v9.y * va.y * vb.y * sc3;
        float2 cm;
        cm.x = fmaxf(fmaxf(b0.x, b1.x), fmaxf(b2.x, b3.x));
        cm.y = fmaxf(fmaxf(b0.y, b1.y), fmaxf(b2.y, b3.y));
        float2 nmx;
        nmx.x = fmaxf(mx.x, cm.x);
        nmx.y = fmaxf(mx.y, cm.y);
        float2 ps;
        ps.x = __expf((b0.x - nmx.x) * 100.0f) + __expf((b1.x - nmx.x) * 100.0f) +
               __expf((b2.x - nmx.x) * 100.0f) + __expf((b3.x - nmx.x) * 100.0f);
        ps.y = __expf((b0.y - nmx.y) * 100.0f) + __expf((b1.y - nmx.y) * 100.0f) +
               __expf((b2.y - nmx.y) * 100.0f) + __expf((b3.y - nmx.y) * 100.0f);
        sum.x = sum.x * __expf((mx.x - nmx.x) * 100.0f) + ps.x;
        sum.y = sum.y * __expf((mx.y - nmx.y) * 100.0f) + ps.y;
        mx = nmx;
    }
    float2 lse;
    lse.x = mx.x + 0.01f * __logf(sum.x);
    lse.y = mx.y + 0.01f * __logf(sum.y);

    const int gi = r0 + rowloc;                      // global row (c,g)
    *(float2*)(r_out + gi * B_ + 2 * bh) = lse;

    // per-clause max partials -> atomic
    float m = fmaxf(lse.x, lse.y);
#pragma unroll
    for (int o = 32; o; o >>= 1) m = fmaxf(m, __shfl_xor(m, o, 64));
    const int lane = tid & 63, wv = tid >> 6;
    if (lane == 0) sRed[wv] = m;
    __syncthreads();
    if (tid == 0) {
        float a = fmaxf(fmaxf(sRed[0], sRed[1]), fmaxf(sRed[2], sRed[3]));
        atomicMaxPos(&cmax_step[c * 16], a);
    }
}

// ---- combine: acc = softor2(Rold*sc, r*scr), float4, gmax atomic ----
__global__ __launch_bounds__(256, 8) void k_combine(const float* __restrict__ Rold,
                                                    int mask,                     // 65535 at t=0
                                                    const float* __restrict__ r_in,
                                                    float* __restrict__ Rnew,     // buf0
                                                    const float* __restrict__ gmax_prev,
                                                    const float* __restrict__ cmax_step,
                                                    float* __restrict__ gmax_out) {
    __shared__ float sRed[4];
    const int tid = threadIdx.x;
    const int i4 = (blockIdx.x * 256 + tid) * 4;     // 512 blocks cover 524288 items
    const int c = i4 >> 16;

    const float gm = gmax_prev ? gmax_prev[0] : 0.0f;
    const float sc = (gm > 1.0f) ? (1.0f / gm) : 1.0f;
    const float cmv = cmax_step[c * 16];
    const float scr = (cmv > 1.0f) ? (1.0f / cmv) : 1.0f;

    const float4 Ro = *(const float4*)(Rold + (i4 & mask));
    const float4 rv = *(const float4*)(r_in + i4);
    float4 o;
    {
        float Rn = Ro.x * sc, rn = rv.x * scr;
        float M = fmaxf(Rn, rn), mn = fminf(Rn, rn);
        o.x = M + 0.01f * __logf(1.0f + __expf((mn - M) * 100.0f));
    }
    {
        float Rn = Ro.y * sc, rn = rv.y * scr;
        float M = fmaxf(Rn, rn), mn = fminf(Rn, rn);
        o.y = M + 0.01f * __logf(1.0f + __expf((mn - M) * 100.0f));
    }
    {
        float Rn = Ro.z * sc, rn = rv.z * scr;
        float M = fmaxf(Rn, rn), mn = fminf(Rn, rn);
        o.z = M + 0.01f * __logf(1.0f + __expf((mn - M) * 100.0f));
    }
    {
        float Rn = Ro.w * sc, rn = rv.w * scr;
        float M = fmaxf(Rn, rn), mn = fminf(Rn, rn);
        o.w = M + 0.01f * __logf(1.0f + __expf((mn - M) * 100.0f));
    }
    *(float4*)(Rnew + i4) = o;

    float mm = fmaxf(fmaxf(o.x, o.y), fmaxf(o.z, o.w));
#pragma unroll
    for (int off = 32; off; off >>= 1) mm = fmaxf(mm, __shfl_xor(mm, off, 64));
    const int lane = tid & 63, wv = tid >> 6;
    if (lane == 0) sRed[wv] = mm;
    __syncthreads();
    if (tid == 0) {
        float a = fmaxf(fmaxf(sRed[0], sRed[1]), fmaxf(sRed[2], sRed[3]));
        atomicMaxPos(gmax_out, a);
    }
}

// ---- out: transpose [C][G][B] -> [C][B][G] with final global-max scale ----
__global__ __launch_bounds__(256) void k_out(const float* __restrict__ buf0,
                                             const float* __restrict__ gmaxslot,
                                             float* __restrict__ out) {
    __shared__ float sT[64 * 33];
    const int bid = blockIdx.x;        // 256 blocks
    const int c = bid >> 5;
    const int g0 = (bid & 31) << 6;
    const int tid = threadIdx.x;

    const float gm = gmaxslot[0];
    const float sc = (gm > 1.0f) ? (1.0f / gm) : 1.0f;

    const float* src = buf0 + (c * G_ + g0) * B_;
#pragma unroll
    for (int k = 0; k < 8; ++k) {
        int j = tid + 256 * k;
        sT[(j >> 5) * 33 + (j & 31)] = src[j] * sc;
    }
    __syncthreads();
#pragma unroll
    for (int k = 0; k < 8; ++k) {
        int j = tid + 256 * k;
        int b = j >> 6, gg = j & 63;
        out[(c * B_ + b) * G_ + g0 + gg] = sT[gg * 33 + b];
    }
}

extern "C" void kernel_launch(void* const* d_in, const int* in_sizes, int n_in,
                              void* d_out, int out_size, void* d_ws, size_t ws_size,
                              hipStream_t stream) {
    const float* x = (const float*)d_in[0];
    const int* I = (const int*)d_in[1];
    float* out = (float*)d_out;
    float* ws = (float*)d_ws;

    float* buf0 = ws + OFF_BUF0;
    float* buf1 = ws + OFF_BUF1;
    float* maxs = ws + OFF_MAX;         // cmax slots
    float* gmax = ws + OFF_GMAX;        // gmax slots
    float* xT = ws + OFF_XT;

    k_init<<<64, 1024, 0, stream>>>(x, xT, maxs);

    for (int t = 0; t < 4; ++t) {
        const float* Rsrc = (t == 0) ? xT : buf0;
        const int cs = (t == 0) ? 0 : GB_;
        const float* gprev = (t == 0) ? nullptr : (gmax + (t - 1) * 16);
        float* cstep = maxs + t * 128;
        const int mask = (t == 0) ? (GB_ - 1) : 0x7FFFFFFF;

        k_clause<<<1024, 256, 0, stream>>>(Rsrc, cs, I, buf1, gprev, cstep);
        k_combine<<<512, 256, 0, stream>>>(Rsrc, mask, buf1, buf0, gprev, cstep,
                                           gmax + t * 16);
    }

    k_out<<<256, 256, 0, stream>>>(buf0, gmax + 48, out);
}

// Round 8
// 95.691 us; speedup vs baseline: 1.2225x; 1.2225x over previous
//
#include <hip/hip_runtime.h>
#include <hip/hip_bf16.h>

#define C_ 8
#define B_ 32
#define G_ 2048
#define S_ 32
#define L_ 3
#define GB_ (G_ * B_)                 // 65536 items per clause

// R layout (buf0, buf1, xT): bq-major  [c][b/4][g][4]  (xT: [b/4][g][4])
//   flat index inside a clause: bq*8192 + g*4 + (b&3)   (65536 floats per clause)

// ws float offsets
#define OFF_BUF0 0                     // [C][8][G][4] unnormalized R (gather source)
#define OFF_BUF1 524288                // [C][8][G][4] clause lse r
#define OFF_MAX  1048576               // cmax slots: (t*8+c)*16 -> 512 floats
#define OFF_GMAX (OFF_MAX + 512)       // gmax slots: t*16 -> 64 floats
#define OFF_XT   (OFF_MAX + 640)       // xT [8][G][4]
#define ZERO_FLOATS 576

__device__ __forceinline__ void atomicMaxPos(float* a, float v) {
    // all values >= 0, so uint compare == float compare
    atomicMax((unsigned*)a, __float_as_uint(v));
}

// ---- build xT[bq][g][b3] = x[b][g]; zero the max slots ----
__global__ __launch_bounds__(1024) void k_init(const float* __restrict__ x,
                                               float* __restrict__ xT,
                                               float* __restrict__ maxs) {
    __shared__ float sT[32 * 33];
    const int tid = threadIdx.x, bid = blockIdx.x;    // 64 blocks x 1024
    const int g0 = bid * 32;
    // read x coalesced: b = tid>>5, gloc = tid&31
    sT[(tid & 31) * 33 + (tid >> 5)] = x[(tid >> 5) * G_ + g0 + (tid & 31)];
    __syncthreads();
    // write bq-major: gloc = tid>>5, b = tid&31
    {
        const int gloc = tid >> 5, b = tid & 31;
        xT[(b >> 2) * (G_ * 4) + (g0 + gloc) * 4 + (b & 3)] = sT[gloc * 33 + b];
    }
    if (bid == 0 && tid < ZERO_FLOATS) maxs[tid] = 0.0f;
}

// ---- clause: LDS-staged slice gather ----
// 512 blocks: c = bid>>6, bh(b-quad) = (bid>>3)&7, gs = bid&7 (256 g-rows each)
__global__ __launch_bounds__(256, 2) void k_clause(const float* __restrict__ Rbase,
                                                   int cstride,                 // 0 at t=0
                                                   const int* __restrict__ I,
                                                   float* __restrict__ r_out,   // buf1
                                                   const float* __restrict__ gmax_prev,
                                                   float* __restrict__ cmax_step) {
    __shared__ float sR[G_ * 4];        // 32 KB: this (c, b-quad) slice, all g
    __shared__ float sRed[4];

    const int tid = threadIdx.x;
    const int bid = blockIdx.x;
    const int c = bid >> 6;
    const int bh = (bid >> 3) & 7;
    const int gs = bid & 7;

    // stage slice: fully contiguous (bq-major layout), 2048 float4
    {
        const float4* src = (const float4*)(Rbase + c * cstride + bh * (G_ * 4));
        float4* dst = (float4*)sR;
#pragma unroll
        for (int k = 0; k < 8; ++k) dst[tid + k * 256] = src[tid + k * 256];
    }
    __syncthreads();

    const float gm = gmax_prev ? gmax_prev[0] : 0.0f;
    const float sc = (gm > 1.0f) ? (1.0f / gm) : 1.0f;
    const float sc3 = sc * sc * sc;

    const int bh2 = tid & 1;                       // float2 within the quad
    const float2* sR2 = (const float2*)sR + bh2;   // element g -> sR2[g*2]

    float blockm = -1e30f;

#pragma unroll 1
    for (int pass = 0; pass < 2; ++pass) {
        const int row = gs * 256 + pass * 128 + (tid >> 1);
        const int4* p = (const int4*)(I + (c * G_ + row) * 96);

        float2 mx = make_float2(-1e30f, -1e30f);
        float2 sum = make_float2(0.0f, 0.0f);
#pragma unroll
        for (int ch = 0; ch < 8; ++ch) {           // 4 substitutions per chunk
            const int4 qa = p[ch * 3 + 0], qb = p[ch * 3 + 1], qc = p[ch * 3 + 2];
            const float2 v0 = sR2[qa.x << 1], v1 = sR2[qa.y << 1], v2 = sR2[qa.z << 1];
            const float2 v3 = sR2[qa.w << 1], v4 = sR2[qb.x << 1], v5 = sR2[qb.y << 1];
            const float2 v6 = sR2[qb.z << 1], v7 = sR2[qb.w << 1], v8 = sR2[qc.x << 1];
            const float2 v9 = sR2[qc.y << 1], va = sR2[qc.z << 1], vb = sR2[qc.w << 1];
            float2 b0, b1, b2, b3;
            b0.x = v0.x * v1.x * v2.x * sc3;  b0.y = v0.y * v1.y * v2.y * sc3;
            b1.x = v3.x * v4.x * v5.x * sc3;  b1.y = v3.y * v4.y * v5.y * sc3;
            b2.x = v6.x * v7.x * v8.x * sc3;  b2.y = v6.y * v7.y * v8.y * sc3;
            b3.x = v9.x * va.x * vb.x * sc3;  b3.y = v9.y * va.y * vb.y * sc3;
            float2 cm;
            cm.x = fmaxf(fmaxf(b0.x, b1.x), fmaxf(b2.x, b3.x));
            cm.y = fmaxf(fmaxf(b0.y, b1.y), fmaxf(b2.y, b3.y));
            float2 nmx;
            nmx.x = fmaxf(mx.x, cm.x);
            nmx.y = fmaxf(mx.y, cm.y);
            float2 ps;
            ps.x = __expf((b0.x - nmx.x) * 100.0f) + __expf((b1.x - nmx.x) * 100.0f) +
                   __expf((b2.x - nmx.x) * 100.0f) + __expf((b3.x - nmx.x) * 100.0f);
            ps.y = __expf((b0.y - nmx.y) * 100.0f) + __expf((b1.y - nmx.y) * 100.0f) +
                   __expf((b2.y - nmx.y) * 100.0f) + __expf((b3.y - nmx.y) * 100.0f);
            sum.x = sum.x * __expf((mx.x - nmx.x) * 100.0f) + ps.x;
            sum.y = sum.y * __expf((mx.y - nmx.y) * 100.0f) + ps.y;
            mx = nmx;
        }
        float2 lse;
        lse.x = mx.x + 0.01f * __logf(sum.x);
        lse.y = mx.y + 0.01f * __logf(sum.y);

        // write r in bq-major layout
        *(float2*)(r_out + ((c * 8 + bh) * G_ + row) * 4 + bh2 * 2) = lse;
        blockm = fmaxf(blockm, fmaxf(lse.x, lse.y));
    }

    // per-clause max partials -> atomic (block is single-clause)
    float m = blockm;
#pragma unroll
    for (int o = 32; o; o >>= 1) m = fmaxf(m, __shfl_xor(m, o, 64));
    const int lane = tid & 63, wv = tid >> 6;
    if (lane == 0) sRed[wv] = m;
    __syncthreads();
    if (tid == 0) {
        float a = fmaxf(fmaxf(sRed[0], sRed[1]), fmaxf(sRed[2], sRed[3]));
        atomicMaxPos(&cmax_step[c * 16], a);
    }
}

// ---- combine: acc = softor2(Rold*sc, r*scr), float4, gmax atomic ----
// elementwise in bq-major layout (c = i >> 16 still holds)
__global__ __launch_bounds__(256, 8) void k_combine(const float* __restrict__ Rold,
                                                    int mask,                     // GB_-1 at t=0
                                                    const float* __restrict__ r_in,
                                                    float* __restrict__ Rnew,     // buf0
                                                    const float* __restrict__ gmax_prev,
                                                    const float* __restrict__ cmax_step,
                                                    float* __restrict__ gmax_out) {
    __shared__ float sRed[4];
    const int tid = threadIdx.x;
    const int i4 = (blockIdx.x * 256 + tid) * 4;     // 512 blocks cover 524288 items
    const int c = i4 >> 16;

    const float gm = gmax_prev ? gmax_prev[0] : 0.0f;
    const float sc = (gm > 1.0f) ? (1.0f / gm) : 1.0f;
    const float cmv = cmax_step[c * 16];
    const float scr = (cmv > 1.0f) ? (1.0f / cmv) : 1.0f;

    const float4 Ro = *(const float4*)(Rold + (i4 & mask));
    const float4 rv = *(const float4*)(r_in + i4);
    float4 o;
    {
        float Rn = Ro.x * sc, rn = rv.x * scr;
        float M = fmaxf(Rn, rn), mn = fminf(Rn, rn);
        o.x = M + 0.01f * __logf(1.0f + __expf((mn - M) * 100.0f));
    }
    {
        float Rn = Ro.y * sc, rn = rv.y * scr;
        float M = fmaxf(Rn, rn), mn = fminf(Rn, rn);
        o.y = M + 0.01f * __logf(1.0f + __expf((mn - M) * 100.0f));
    }
    {
        float Rn = Ro.z * sc, rn = rv.z * scr;
        float M = fmaxf(Rn, rn), mn = fminf(Rn, rn);
        o.z = M + 0.01f * __logf(1.0f + __expf((mn - M) * 100.0f));
    }
    {
        float Rn = Ro.w * sc, rn = rv.w * scr;
        float M = fmaxf(Rn, rn), mn = fminf(Rn, rn);
        o.w = M + 0.01f * __logf(1.0f + __expf((mn - M) * 100.0f));
    }
    *(float4*)(Rnew + i4) = o;

    float mm = fmaxf(fmaxf(o.x, o.y), fmaxf(o.z, o.w));
#pragma unroll
    for (int off = 32; off; off >>= 1) mm = fmaxf(mm, __shfl_xor(mm, off, 64));
    const int lane = tid & 63, wv = tid >> 6;
    if (lane == 0) sRed[wv] = mm;
    __syncthreads();
    if (tid == 0) {
        float a = fmaxf(fmaxf(sRed[0], sRed[1]), fmaxf(sRed[2], sRed[3]));
        atomicMaxPos(gmax_out, a);
    }
}

// ---- out: bq-major [C][8][G][4] -> [C][B][G] with final global-max scale ----
__global__ __launch_bounds__(256) void k_out(const float* __restrict__ buf0,
                                             const float* __restrict__ gmaxslot,
                                             float* __restrict__ out) {
    __shared__ float sT[32 * 65];
    const int bid = blockIdx.x;        // 256 = 8 c x 32 g-chunks of 64
    const int c = bid >> 5;
    const int g0 = (bid & 31) << 6;
    const int tid = threadIdx.x;

    const float gm = gmaxslot[0];
    const float sc = (gm > 1.0f) ? (1.0f / gm) : 1.0f;

    const int r = tid >> 2, w = tid & 3;
#pragma unroll
    for (int k = 0; k < 8; ++k) {      // k = b-quad; reads fully contiguous per k
        sT[(k * 4 + w) * 65 + r] = buf0[((c * 8 + k) * G_ + g0 + r) * 4 + w] * sc;
    }
    __syncthreads();
#pragma unroll
    for (int k = 0; k < 8; ++k) {
        const int j = tid + k * 256;
        const int b = j >> 6, gg = j & 63;
        out[(c * B_ + b) * G_ + g0 + gg] = sT[b * 65 + gg];   // coalesced
    }
}

extern "C" void kernel_launch(void* const* d_in, const int* in_sizes, int n_in,
                              void* d_out, int out_size, void* d_ws, size_t ws_size,
                              hipStream_t stream) {
    const float* x = (const float*)d_in[0];
    const int* I = (const int*)d_in[1];
    float* out = (float*)d_out;
    float* ws = (float*)d_ws;

    float* buf0 = ws + OFF_BUF0;
    float* buf1 = ws + OFF_BUF1;
    float* maxs = ws + OFF_MAX;         // cmax slots
    float* gmax = ws + OFF_GMAX;        // gmax slots
    float* xT = ws + OFF_XT;

    k_init<<<64, 1024, 0, stream>>>(x, xT, maxs);

    for (int t = 0; t < 4; ++t) {
        const float* Rsrc = (t == 0) ? xT : buf0;
        const int cs = (t == 0) ? 0 : GB_;
        const float* gprev = (t == 0) ? nullptr : (gmax + (t - 1) * 16);
        float* cstep = maxs + t * 128;
        const int mask = (t == 0) ? (GB_ - 1) : 0x7FFFFFFF;   // strip clause bits only

        k_clause<<<512, 256, 0, stream>>>(Rsrc, cs, I, buf1, gprev, cstep);
        k_combine<<<512, 256, 0, stream>>>(Rsrc, mask, buf1, buf0, gprev, cstep,
                                           gmax + t * 16);
    }

    k_out<<<256, 256, 0, stream>>>(buf0, gmax + 48, out);
}